// Round 9
// baseline (364.533 us; speedup 1.0000x reference)
//
#include <hip/hip_runtime.h>

// Problem constants (match reference)
constexpr int   T_STEPS = 64;
constexpr int   NN      = 2048;
constexpr float DT_TAU  = 0.1f;    // DT * TAU_MEM_INV
constexpr float V_TH_C  = 1.0f;
constexpr float TRC     = 0.05f;   // DT * TAU_PRE_INV == DT * TAU_POST_INV
constexpr float ETA     = 1e-3f;   // ETA_PLUS == ETA_MINUS

// 256 blocks x 512 threads (cooperative, 1 block/CU). Block b owns neurons
// [8b, 8b+8); wave w owns neuron 8b+w (w-row in 32 VGPR/lane; v/tpo/isyn
// replicated across its 64 lanes). z/tp replicated per block in LDS (split-
// slot layout), rebuilt each step from the exchanged spike words.
//
// HARD-WON EXCHANGE RULES (r1/r2/r4/r5/r6/r8):
//  - Per-line request rate at the MALL is THE governing variable. r2: private
//    128B lines 244->203. r5: 512 pollers/line 181->217. r8: poll-prefetch +
//    early-start polling (one barrier) re-added line pressure, 181->232.
//  - Publish via LDS arrive-RMW, triggered by the 8th arriver (r4: 203->181).
//  - LDS bank conflicts 2-8M are fully hidden under the exchange wait
//    (r4 2.58M == r6 8.26M == ~181us). Phase-C reads stride-1 anyway.
//
// ROUND 9: PUSH exchange (single-writer/single-reader mailboxes).
// Pull model's floor: every published word is polled by 256 blocks -> 256
// requesters/line, irreducible. Push model: producer b writes its word into
// a PRIVATE mailbox per consumer: push[par][c][b]. Consumer polls only its
// own 2KB region (16 lines, 16 pollers each, ALL from this block) -> per-line
// traffic ~12x lower; publish stores never queue behind a poll storm.
//   a. LIF; lane0: raster store + ds-atomic arrive on word_s[par]
//      (add (1<<24)|(z<<wv)). No global publish by the 8th arriver.
//   push: threads tid<256 spin on word_s[par] until count==8 (LDS broadcast
//      read), then each stores ((k+1)<<32|bits) to consumer tid's mailbox
//      slot [bid] — 256 wave-parallel fire-and-forget stores.
//   b. poller tid polls its OWN mailbox word [bid][tid] for tag k+1; unpack
//      8 neurons to z_s split-slots; tp persistent in poller regs (tpA/tpB).
//      __syncthreads  (RAW: b-writes before C-reads)
//      tid0 resets word_s[par] for reuse at k+2 (ordered before a(k+2)
//      arrivals by this step's post-C barrier).
//   c. fused STDP w-update + matvec (split-slot reads, bit-exact c=0..7
//      xyzw order); butterfly -> isyn in regs; prefetch next x.
//      __syncthreads  (WAR: C-reads before next b-writes)
//
// Safety (push): each mailbox word has ONE writer (block b thread c) and ONE
// reader (block c poller b). Overwrite gating: b writes (par,c,b) tag k+3
// only after b's b(k+1) consumed c's tag-k+2 word, which required c's a(k+1)
// push, which follows c's post-b/post-C barriers of step k, i.e. c consumed
// tag k+1 -> '!=' spin never misses. Stale-run tags (<=63 left at exit) are
// overwritten at this run's a(0)/a(1) (program order precedes any aliasing
// expectation at k=60+); 0x00/0xAA poison never matches tags 1..64. word_s
// reset (tid0, step k) is read-free until a(k+2) via barriers. pusher spin
// reads complete before post-b barrier; reset is after it -> race-free.
// Workspace: 2*256*256*8B = 1MB. If ws < 1MB -> r6 pull fallback (private
// 128B lines, 8th-arriver publish), bit-identical output either way.
constexpr int BLOCKS  = 256;
constexpr int THREADS = 512;
constexpr int ROWS_PER_BLOCK = NN / BLOCKS;   // 8 == waves per block
constexpr int CHUNKS = NN / 256;              // 8 float4 chunks per lane

__global__ __launch_bounds__(THREADS)
void snn_msg_kernel(const float* __restrict__ x,       // [T, N]
                    const float* __restrict__ w_in,    // [N, N] pristine (never written)
                    const float* __restrict__ tpre0,   // [N]
                    const float* __restrict__ tpost0,  // [N]
                    unsigned long long* __restrict__ zpub, // pull: [2][B*stride]; push: [2][B][B]
                    int stride,                        // pull-mode u64 stride
                    int push_mode,                     // 1 = mailbox exchange
                    float*       __restrict__ out)     // [T, N] spikes
{
    const int bid  = blockIdx.x;
    const int tid  = threadIdx.x;
    const int wv   = tid >> 6;
    const int lane = tid & 63;
    const int row  = bid * ROWS_PER_BLOCK + wv;   // this wave's neuron / w row

    __shared__ __align__(16) float z_s[NN];       // spike vector (split-slot layout)
    __shared__ __align__(16) float tp_s[NN];      // pre-trace mirror (split-slot)
    __shared__ __align__(16) float x_s[T_STEPS * ROWS_PER_BLOCK]; // owned inputs
    __shared__ unsigned word_s[2];                // [parity] count<<24 | bits

    // Poller tid (<256) owns neurons [8tid, 8tid+8): tp persistent in regs.
    float4 tpA = make_float4(0.f, 0.f, 0.f, 0.f);
    float4 tpB = tpA;
    if (tid < BLOCKS) {
        tpA = ((const float4*)tpre0)[2 * tid];
        tpB = ((const float4*)tpre0)[2 * tid + 1];
    }

    // Stage ALL owned inputs x[t][8b..8b+8) into LDS once.
    x_s[tid] = x[(size_t)(tid >> 3) * NN + bid * ROWS_PER_BLOCK + (tid & 7)];

    if (tid < 2) word_s[tid] = 0u;

    // Own-neuron state, replicated across all 64 lanes.
    float v_own   = 0.0f;
    float tpo_own = tpost0[row];          // broadcast load

    // This wave's w row: chunk c holds w[row][(c*64+lane)*4 ..+3].
    const float4* wrow4 = (const float4*)(w_in + (size_t)row * NN);
    float4 wreg[CHUNKS];
    #pragma unroll
    for (int c = 0; c < CHUNKS; ++c) wreg[c] = wrow4[c * 64 + lane];

    // Per-lane constant base for the split-slot permutation (phase C reads).
    const int perm_base = (lane >> 1) + 256 * (lane & 1);

    float isyn = 0.0f;                    // w @ z carry, lives in registers
    float xk   = 0.0f;                    // prefetched input current
    __syncthreads();
    xk = x_s[wv];                         // x[0][row] (post-barrier: x_s ready)

    for (int k = 0; k < T_STEPS; ++k) {
        const int par = k & 1;

        // ---- a: LIF (all lanes redundantly); lane0 raster + arrive ----
        float v = v_own + DT_TAU * ((0.0f - v_own) + isyn + xk);
        float z = (v - V_TH_C > 0.0f) ? 1.0f : 0.0f;
        v_own   = v * (1.0f - z);
        tpo_own = tpo_own + TRC * (-tpo_own + z);   // post-trace (post-update
                                                    // value feeds C, as in ref)
        if (lane == 0) {
            out[(size_t)k * NN + row] = z;          // fire-and-forget raster
            if (k + 1 < T_STEPS) {
                unsigned add = 0x01000000u | (z > 0.0f ? (1u << wv) : 0u);
                unsigned old = __hip_atomic_fetch_add(&word_s[par], add,
                                   __ATOMIC_RELAXED, __HIP_MEMORY_SCOPE_WORKGROUP);
                if (!push_mode && (old >> 24) == 7u) {  // pull: 8th arriver publishes
                    unsigned bits = (old + add) & 0xFFu;
                    __hip_atomic_store(&word_s[par], 0u,
                                       __ATOMIC_RELAXED, __HIP_MEMORY_SCOPE_WORKGROUP);
                    unsigned long long wrd =
                        ((unsigned long long)(unsigned)(k + 1) << 32) | bits;
                    __hip_atomic_store(&zpub[(size_t)(par * BLOCKS + bid) * stride],
                                       wrd, __ATOMIC_RELAXED,
                                       __HIP_MEMORY_SCOPE_AGENT);
                }
            }
        }
        if (k == T_STEPS - 1) break;   // raster[63] written; no exchange needed

        // ---- push + b: exchange, then unpack to split slots ----
        if (tid < BLOCKS) {
            unsigned long long pv;
            if (push_mode) {
                // pusher: wait for the block word (LDS broadcast spin), then
                // store it into consumer tid's mailbox slot [bid].
                unsigned wrd = __hip_atomic_load(&word_s[par],
                                   __ATOMIC_RELAXED, __HIP_MEMORY_SCOPE_WORKGROUP);
                while ((wrd >> 24) != 8u)
                    wrd = __hip_atomic_load(&word_s[par],
                              __ATOMIC_RELAXED, __HIP_MEMORY_SCOPE_WORKGROUP);
                unsigned long long myword =
                    ((unsigned long long)(unsigned)(k + 1) << 32) | (wrd & 0xFFu);
                __hip_atomic_store(
                    &zpub[((size_t)par * BLOCKS + tid) * BLOCKS + bid],
                    myword, __ATOMIC_RELAXED, __HIP_MEMORY_SCOPE_AGENT);
                // poll OWN mailbox word [bid][tid]: single writer, 16 same-
                // block pollers per 128B line -> no cross-block line sharing.
                const unsigned long long* p =
                    &zpub[((size_t)par * BLOCKS + bid) * BLOCKS + tid];
                pv = __hip_atomic_load(p, __ATOMIC_RELAXED,
                                       __HIP_MEMORY_SCOPE_AGENT);
                while ((unsigned)(pv >> 32) != (unsigned)(k + 1)) {
                    __builtin_amdgcn_s_sleep(1);   // ~64cy backoff
                    pv = __hip_atomic_load(p, __ATOMIC_RELAXED,
                                           __HIP_MEMORY_SCOPE_AGENT);
                }
            } else {
                // pull fallback (r6): poll block tid's private line.
                const unsigned long long* p =
                    &zpub[(size_t)(par * BLOCKS + tid) * stride];
                pv = __hip_atomic_load(p, __ATOMIC_RELAXED,
                                       __HIP_MEMORY_SCOPE_AGENT);
                while ((unsigned)(pv >> 32) != (unsigned)(k + 1)) {
                    __builtin_amdgcn_s_sleep(1);   // ~64cy backoff
                    pv = __hip_atomic_load(p, __ATOMIC_RELAXED,
                                           __HIP_MEMORY_SCOPE_AGENT);
                }
            }
            const unsigned bits = (unsigned)pv;   // z of neurons 8*tid..8*tid+7
            float4 zA, zB;
            zA.x = (bits & 0x01u) ? 1.0f : 0.0f;
            zA.y = (bits & 0x02u) ? 1.0f : 0.0f;
            zA.z = (bits & 0x04u) ? 1.0f : 0.0f;
            zA.w = (bits & 0x08u) ? 1.0f : 0.0f;
            zB.x = (bits & 0x10u) ? 1.0f : 0.0f;
            zB.y = (bits & 0x20u) ? 1.0f : 0.0f;
            zB.z = (bits & 0x40u) ? 1.0f : 0.0f;
            zB.w = (bits & 0x80u) ? 1.0f : 0.0f;
            // identical per-element expression as always -> bit-exact
            tpA.x = tpA.x + TRC * (-tpA.x + zA.x);
            tpA.y = tpA.y + TRC * (-tpA.y + zA.y);
            tpA.z = tpA.z + TRC * (-tpA.z + zA.z);
            tpA.w = tpA.w + TRC * (-tpA.w + zA.w);
            tpB.x = tpB.x + TRC * (-tpB.x + zB.x);
            tpB.y = tpB.y + TRC * (-tpB.y + zB.y);
            tpB.z = tpB.z + TRC * (-tpB.z + zB.z);
            tpB.w = tpB.w + TRC * (-tpB.w + zB.w);
            // split-slot stores: both instructions stride-1 across the wave
            ((float4*)z_s)[tid]          = zA;
            ((float4*)z_s)[tid + BLOCKS] = zB;
            ((float4*)tp_s)[tid]          = tpA;
            ((float4*)tp_s)[tid + BLOCKS] = tpB;
        }
        __syncthreads();               // RAW: b-writes -> C-reads

        // push mode: reset arrive word for reuse at k+2. All pusher reads of
        // this epoch finished before the barrier above; next arrivals on this
        // parity are at a(k+2), ordered after this step's post-C barrier.
        if (push_mode && tid == 0)
            __hip_atomic_store(&word_s[par], 0u,
                               __ATOMIC_RELAXED, __HIP_MEMORY_SCOPE_WORKGROUP);

        // ---- c: fused STDP w-update + matvec (bit-exact order: c=0..7, xyzw) ----
        // Do not refactor into FMA (rounding would drift w, can flip spikes).
        const float zi_own = z;        // own neuron's spike
        const float tpoi   = tpo_own;  // own neuron's post-trace
        xk = x_s[(k + 1) * ROWS_PER_BLOCK + wv];   // prefetch next input
        float acc = 0.0f;
        const float4* z4s  = (const float4*)z_s;
        const float4* tp4s = (const float4*)tp_s;
        #pragma unroll
        for (int c = 0; c < CHUNKS; ++c) {
            const int slot = c * 32 + perm_base;   // split-slot permutation
            float4 zj = z4s[slot];
            float4 tj = tp4s[slot];
            float nw;
            nw = wreg[c].x + (ETA * (zi_own * tj.x) - ETA * (tpoi * zj.x));
            nw = fminf(fmaxf(nw, 0.0f), 1.0f); wreg[c].x = nw; acc += nw * zj.x;
            nw = wreg[c].y + (ETA * (zi_own * tj.y) - ETA * (tpoi * zj.y));
            nw = fminf(fmaxf(nw, 0.0f), 1.0f); wreg[c].y = nw; acc += nw * zj.y;
            nw = wreg[c].z + (ETA * (zi_own * tj.z) - ETA * (tpoi * zj.z));
            nw = fminf(fmaxf(nw, 0.0f), 1.0f); wreg[c].z = nw; acc += nw * zj.z;
            nw = wreg[c].w + (ETA * (zi_own * tj.w) - ETA * (tpoi * zj.w));
            nw = fminf(fmaxf(nw, 0.0f), 1.0f); wreg[c].w = nw; acc += nw * zj.w;
        }
        #pragma unroll
        for (int m = 32; m >= 1; m >>= 1) acc += __shfl_xor(acc, m, 64);
        isyn = acc;                    // i_syn for step k+1, in registers

        __syncthreads();               // WAR: C-reads -> next b-writes
    }
}

extern "C" void kernel_launch(void* const* d_in, const int* in_sizes, int n_in,
                              void* d_out, int out_size, void* d_ws, size_t ws_size,
                              hipStream_t stream) {
    const float* x     = (const float*)d_in[0];   // [T,N]
    const float* w_in  = (const float*)d_in[1];   // [N,N]
    const float* tpre  = (const float*)d_in[2];   // [N]
    const float* tpost = (const float*)d_in[3];   // [N]
    float*       out   = (float*)d_out;           // [T,N]

    unsigned long long* zpub = (unsigned long long*)d_ws;

    // Push mode needs 2*256*256*8B = 1MB of workspace; otherwise fall back to
    // the r6 pull exchange with line-padded words (64KB for 128B stride).
    int push_mode =
        (ws_size >= (size_t)2 * BLOCKS * BLOCKS * sizeof(unsigned long long)) ? 1 : 0;
    int stride;
    if      (push_mode)                                                       stride = 1;
    else if (ws_size >= (size_t)2 * BLOCKS * 16 * sizeof(unsigned long long)) stride = 16;
    else if (ws_size >= (size_t)2 * BLOCKS *  8 * sizeof(unsigned long long)) stride = 8;
    else                                                                      stride = 1;

    void* args[] = {(void*)&x, (void*)&w_in, (void*)&tpre, (void*)&tpost,
                    (void*)&zpub, (void*)&stride, (void*)&push_mode, (void*)&out};
    hipLaunchCooperativeKernel((void*)snn_msg_kernel,
                               dim3(BLOCKS), dim3(THREADS),
                               args, 0, stream);
}